// Round 6
// baseline (4687.709 us; speedup 1.0000x reference)
//
#include <hip/hip_runtime.h>
#include <hip/hip_fp16.h>

// Problem constants
#define TSTEPS 1024
#define HDIM   1024
#define INDIM  512
#define NGATE  4096     // 4*HDIM
#define NWG_L1  64
#define NWG_L23 64
#define NWG_TOT 128
#define POISON_U 0x7C7C7C7Cu   // f16-pair poison: halves are f16 NaN; |h|<1 can't make it
#define SPIN_MAX (1 << 20)     // deadlock valve: fail loud, never hang

// ---------------------------------------------------------------------------
// R16 post-mortem: predication didn't cut FETCH (150MB) -> poll traffic is
// beyond-L2 at agent scope regardless; cadence 3.4us/step is handoff-bound
// (compute ~0.4us). 34ms outlier dispatch = cold-start poll storm.
// R17: (1) f16-packed h transport: rows 2KB not 4KB -> half the poll loads,
// half the visibility payload (R14-validated numerics; poison-sound).
// (2) 128 WGs total: 64 L1 + 64 L23, L23 wave owns a full unit for BOTH
// layers (64 weight uints/lane resident). 3.4x less poll traffic, smaller
// straggler pool. (3) EARLY h2 store: L23 computes L2, stores h2[t], THEN
// computes L3 -> the tight h2 self-recurrence gains ~L3-compute of
// visibility head-start. h1/h3 have >=1 iteration slack already.
// (4) Tiered spin backoff (1->4->32) quenches cold-start storms.
// ---------------------------------------------------------------------------

typedef _Float16 half2v __attribute__((ext_vector_type(2)));

#define PINU(v) asm volatile("" : "+v"(v))

// both-operands-packed f16 dot pair -> 2x v_fma_mix (R14-validated numerics)
__device__ __forceinline__ float dot2f(unsigned h, unsigned w, float c) {
    half2v a = __builtin_bit_cast(half2v, h);
    half2v b = __builtin_bit_cast(half2v, w);
    c = fmaf((float)a[0], (float)b[0], c);
    c = fmaf((float)a[1], (float)b[1], c);
    return c;
}

// Full-wave sum via DPP adds (VALU pipe; validated R14-R16). Result valid in
// lane 63. row_shr 1,2,4,8 then row_bcast15 (rows 1,3) + row_bcast31 (rows 2,3).
__device__ __forceinline__ float wave_sum64_dpp(float v) {
    int x;
    x = __builtin_amdgcn_update_dpp(0, __float_as_int(v), 0x111, 0xf, 0xf, false); v += __int_as_float(x);
    x = __builtin_amdgcn_update_dpp(0, __float_as_int(v), 0x112, 0xf, 0xf, false); v += __int_as_float(x);
    x = __builtin_amdgcn_update_dpp(0, __float_as_int(v), 0x114, 0xf, 0xf, false); v += __int_as_float(x);
    x = __builtin_amdgcn_update_dpp(0, __float_as_int(v), 0x118, 0xf, 0xf, false); v += __int_as_float(x);
    x = __builtin_amdgcn_update_dpp(0, __float_as_int(v), 0x142, 0xa, 0xf, false); v += __int_as_float(x);
    x = __builtin_amdgcn_update_dpp(0, __float_as_int(v), 0x143, 0xc, 0xf, false); v += __int_as_float(x);
    return v;
}

__device__ __forceinline__ float sigm(float x) { return 1.f / (1.f + __expf(-x)); }
__device__ __forceinline__ float fast_tanh(float x) {
    float t = __expf(-2.f * fabsf(x));
    float r = (1.f - t) / (1.f + t);
    return copysignf(r, x);
}

// single-instruction f32 pair -> packed f16 (v_cvt_pkrtz_f16_f32)
__device__ __forceinline__ unsigned pack_h(float a, float b) {
    auto p = __builtin_amdgcn_cvt_pkrtz(a, b);
    return __builtin_bit_cast(unsigned, p);
}

__device__ __forceinline__ unsigned agent_loadu(const unsigned* p) {
    return __hip_atomic_load(const_cast<unsigned*>(p), __ATOMIC_RELAXED,
                             __HIP_MEMORY_SCOPE_AGENT);
}
__device__ __forceinline__ void agent_storeu(unsigned* p, unsigned v) {
    __hip_atomic_store(p, v, __ATOMIC_RELAXED, __HIP_MEMORY_SCOPE_AGENT);
}

// tiered backoff: short first (steady-state catch), long under storms
__device__ __forceinline__ void spin_sleep(int it) {
    if (it < 4)       __builtin_amdgcn_s_sleep(1);
    else if (it < 16) __builtin_amdgcn_s_sleep(4);
    else              __builtin_amdgcn_s_sleep(32);
}

// ---------------------------------------------------------------------------
// Prep: pack fp32 matrix (rows x 1024) into f16-pair uints (rows x 512), RNE.
// ---------------------------------------------------------------------------
__global__ __launch_bounds__(256) void pack_f16(
    const float* __restrict__ src, unsigned* __restrict__ dst, int n)
{
    int i = blockIdx.x * 256 + threadIdx.x;
    if (i < n) {
        float2 v = *(const float2*)(src + 2 * (size_t)i);
        dst[i] = (unsigned)__half_as_ushort(__float2half(v.x)) |
                 ((unsigned)__half_as_ushort(__float2half(v.y)) << 16);
    }
}

// ---------------------------------------------------------------------------
// GEMM for layer-1 input gates (fp32, one-shot — unchanged, proven)
// ---------------------------------------------------------------------------
#define BM 64
#define BN 64
#define BK 32

__global__ __launch_bounds__(256) void gemm_tn(
    const float* __restrict__ B,
    const float* __restrict__ bias1,
    const float* __restrict__ bias2,
    float* __restrict__ C,
    int M, int N, int K,
    const float* __restrict__ x,
    const float* __restrict__ timev)
{
    __shared__ float As[BK][BM + 4];
    __shared__ float Bs[BK][BN + 4];

    const int tid = threadIdx.x;
    const int mblocks = M / BM;
    const int bm = blockIdx.x % mblocks;
    const int bn = blockIdx.x / mblocks;
    const int t0 = bm * BM;
    const int n0 = bn * BN;

    const int tx = tid & 15;
    const int ty = tid >> 4;

    float acc[4][4] = {{0.f}};

    for (int kc = 0; kc < K; kc += BK) {
#pragma unroll
        for (int i = 0; i < 8; i++) {
            int idx = tid + i * 256;
            int r = idx >> 5;
            int c = idx & 31;
            int col = kc + c;
            int trow = t0 + r;
            float av = (col < INDIM) ? x[(size_t)trow * INDIM + col]
                                     : ((col == INDIM) ? timev[trow] : 0.f);
            As[c][r] = av;
            int nrow = n0 + r;
            Bs[c][r] = (col < K) ? B[(size_t)nrow * K + col] : 0.f;
        }
        __syncthreads();

#pragma unroll
        for (int kk = 0; kk < BK; kk++) {
            float a[4], b[4];
#pragma unroll
            for (int i = 0; i < 4; i++) a[i] = As[kk][ty * 4 + i];
#pragma unroll
            for (int j = 0; j < 4; j++) b[j] = Bs[kk][tx * 4 + j];
#pragma unroll
            for (int i = 0; i < 4; i++)
#pragma unroll
                for (int j = 0; j < 4; j++)
                    acc[i][j] = fmaf(a[i], b[j], acc[i][j]);
        }
        __syncthreads();
    }

#pragma unroll
    for (int i = 0; i < 4; i++) {
        int trow = t0 + ty * 4 + i;
#pragma unroll
        for (int j = 0; j < 4; j++) {
            int n = n0 + tx * 4 + j;
            C[(size_t)trow * N + n] = acc[i][j] + bias1[n] + bias2[n];
        }
    }
}

// ---------------------------------------------------------------------------
// Fused dataflow 3-layer scan. H rows transported as packed f16 pairs
// (512 uints/row). Weight uint j = cols (2j, 2j+1); lane s handles uint
// indices s+64m, m=0..7 -> matching LDS reads shp[s+64m].
// L1 (wg<64): 16 units/WG, wave q owns unit u0+q (4 gates, 32 weight uints).
// L23 (wg>=64): 16 units/WG, wave q owns unit u0+q for BOTH L2 and L3
//   (wi[4][8] + wh[4][8] = 64 weight uints resident; shared weights).
//   Iteration t: L2 tick t (h1[t], h2[t-1]) computed FIRST, h2[t] stored
//   EARLY, then L3 tick t-1 (h2[t-1], h3[t-2]).
// ---------------------------------------------------------------------------
__global__ __launch_bounds__(1024, 4) void fused_scan(
    const unsigned* __restrict__ Wp1,     // packed Whh1, 4096 x 512
    const float* __restrict__ G1,
    const unsigned* __restrict__ Wpi2,    // packed Wih2
    const unsigned* __restrict__ Wph2,    // packed Whh2
    const float* bih2, const float* bhh2,
    const float* h0_1, const float* c0_1,
    const float* h0_2, const float* c0_2,
    const float* h0_3, const float* c0_3,
    unsigned* H1p, unsigned* H2p, unsigned* H3p,  // packed h rows, poisoned
    float* H3f)                                   // fp32 h3 for attention
{
    __shared__ unsigned shp1[512];
    __shared__ unsigned shp2[512];
    __shared__ unsigned shp3[512];
    __shared__ float gbuf[16][4];   // L1 gate sums
    __shared__ float gb2[16];       // L23: h2 values
    __shared__ float gb3[16];       // L23: h3 values

    const int tid = threadIdx.x;
    const int wg  = blockIdx.x;
    const int q   = tid >> 6;      // wave 0..15
    const int s   = tid & 63;

    if (wg < NWG_L1) {
        // ------- Layer 1: WG owns 16 units, wave q owns unit u0+q -------
        const int u0 = wg << 4;
        const int u  = u0 + q;
        unsigned w[4][8];
#pragma unroll
        for (int g = 0; g < 4; ++g) {
            const unsigned* row = Wp1 + (size_t)((g << 10) + u) * 512 + s;
#pragma unroll
            for (int m = 0; m < 8; ++m)
                w[g][m] = row[64 * m];
        }
        float c1 = (tid < 16) ? c0_1[u0 + tid] : 0.f;

        for (int t = 0; t < TSTEPS; ++t) {
#pragma unroll
            for (int g = 0; g < 4; ++g)
#pragma unroll
                for (int m = 0; m < 8; ++m) PINU(w[g][m]);

            float Gv0 = 0.f, Gv1 = 0.f, Gv2 = 0.f, Gv3 = 0.f;
            if (tid < 16) {   // prefetch gate inputs (normal cached loads)
                const float* gptr = G1 + (size_t)t * NGATE + u0 + tid;
                Gv0 = gptr[0];
                Gv1 = gptr[1024];
                Gv2 = gptr[2048];
                Gv3 = gptr[3072];
            }
            // stage packed h1[t-1]
            if (t == 0) {
                if (tid < 512)
                    shp1[tid] = pack_h(h0_1[2 * tid], h0_1[2 * tid + 1]);
            } else if (tid < 512) {
                const unsigned* p = H1p + (size_t)(t - 1) * 512 + tid;
                unsigned v = agent_loadu(p);
                for (int it = 0; it < SPIN_MAX; ++it) {
                    if (__ballot(v == POISON_U) == 0ULL) break;
                    spin_sleep(it);
                    if (v == POISON_U) v = agent_loadu(p);
                }
                shp1[tid] = v;
            }
            __syncthreads();                                   // A: staged

            unsigned hp[8];
#pragma unroll
            for (int m = 0; m < 8; ++m) hp[m] = shp1[s + 64 * m];
            float a0 = 0.f, a1 = 0.f, a2 = 0.f, a3 = 0.f;
#pragma unroll
            for (int m = 0; m < 8; ++m) {
                a0 = dot2f(hp[m], w[0][m], a0);
                a1 = dot2f(hp[m], w[1][m], a1);
                a2 = dot2f(hp[m], w[2][m], a2);
                a3 = dot2f(hp[m], w[3][m], a3);
            }
            a0 = wave_sum64_dpp(a0);
            a1 = wave_sum64_dpp(a1);
            a2 = wave_sum64_dpp(a2);
            a3 = wave_sum64_dpp(a3);
            if (s == 63) {
                gbuf[q][0] = a0;
                gbuf[q][1] = a1;
                gbuf[q][2] = a2;
                gbuf[q][3] = a3;
            }
            __syncthreads();                                   // B: sums ready

            if (tid < 16) {
                float gi = gbuf[tid][0] + Gv0;
                float gf = gbuf[tid][1] + Gv1;
                float gg = gbuf[tid][2] + Gv2;
                float go = gbuf[tid][3] + Gv3;
                float i_ = sigm(gi), f_ = sigm(gf), g_ = fast_tanh(gg), o_ = sigm(go);
                c1 = f_ * c1 + i_ * g_;
                float hn = o_ * fast_tanh(c1);
                float hnn = __shfl_down(hn, 1, 64);
                if (!(tid & 1))
                    agent_storeu(H1p + (size_t)t * 512 + (u0 >> 1) + (tid >> 1),
                                 pack_h(hn, hnn));
            }
        }
    } else {
        // ---- Layers 2 & 3: WG owns 16 units; wave q owns unit u0+q ----
        const int u0    = (wg - NWG_L1) << 4;
        const int u     = u0 + q;
        const int pbase = (wg - NWG_L1) << 3;   // packed row base (8 uints/WG)
        unsigned wi[4][8], wh[4][8];
#pragma unroll
        for (int g = 0; g < 4; ++g) {
            const unsigned* ri = Wpi2 + (size_t)((g << 10) + u) * 512 + s;
            const unsigned* rh = Wph2 + (size_t)((g << 10) + u) * 512 + s;
#pragma unroll
            for (int m = 0; m < 8; ++m) {
                wi[g][m] = ri[64 * m];
                wh[g][m] = rh[64 * m];
            }
        }
        float b0 = 0.f, b1 = 0.f, b2 = 0.f, b3 = 0.f, cs2 = 0.f, cs3 = 0.f;
        if (s == 63) {
            b0 = bih2[u]        + bhh2[u];
            b1 = bih2[1024 + u] + bhh2[1024 + u];
            b2 = bih2[2048 + u] + bhh2[2048 + u];
            b3 = bih2[3072 + u] + bhh2[3072 + u];
            cs2 = c0_2[u];
            cs3 = c0_3[u];
        }

        // iteration t: L2 tick t (h1[t], h2[t-1]); L3 tick t-1 (h2[t-1], h3[t-2])
        for (int t = 0; t <= TSTEPS; ++t) {
#pragma unroll
            for (int g = 0; g < 4; ++g)
#pragma unroll
                for (int m = 0; m < 8; ++m) { PINU(wi[g][m]); PINU(wh[g][m]); }

            const bool do2 = (t < TSTEPS);
            const bool do3 = (t >= 1);

            // ---- stage: tid<512 own the TIGHT row h2[t-1]; others h1/h3 ----
            if (tid < 512) {
                if (t == 0) {
                    shp2[tid] = pack_h(h0_2[2 * tid], h0_2[2 * tid + 1]);
                } else {
                    const unsigned* p = H2p + (size_t)(t - 1) * 512 + tid;
                    unsigned v = agent_loadu(p);
                    for (int it = 0; it < SPIN_MAX; ++it) {
                        if (__ballot(v == POISON_U) == 0ULL) break;
                        spin_sleep(it);
                        if (v == POISON_U) v = agent_loadu(p);
                    }
                    shp2[tid] = v;
                }
            } else {
                const int sid = tid - 512;
                const bool w1 = do2;       // h1[t]
                const bool w3 = (t > 1);   // h3[t-2]
                const unsigned* p1 = H1p + (size_t)t * 512 + sid;
                const unsigned* p3 = H3p + (size_t)(t - 2) * 512 + sid;
                unsigned v1 = 0u, v3 = 0u;
                if (w1) v1 = agent_loadu(p1);
                if (w3) v3 = agent_loadu(p3);
                for (int it = 0; it < SPIN_MAX; ++it) {
                    bool bad = (w1 && v1 == POISON_U) || (w3 && v3 == POISON_U);
                    if (__ballot(bad) == 0ULL) break;
                    spin_sleep(it);
                    if (w1 && v1 == POISON_U) v1 = agent_loadu(p1);
                    if (w3 && v3 == POISON_U) v3 = agent_loadu(p3);
                }
                shp1[sid] = v1;
                shp3[sid] = (t == 1) ? pack_h(h0_3[2 * sid], h0_3[2 * sid + 1]) : v3;
            }
            __syncthreads();                                   // A: staged

            // ---- Phase L2 (first -> early h2 store) ----
            if (do2) {
                unsigned ha[8], hb[8];
#pragma unroll
                for (int m = 0; m < 8; ++m) {
                    ha[m] = shp1[s + 64 * m];
                    hb[m] = shp2[s + 64 * m];
                }
                float a0 = 0.f, a1 = 0.f, a2 = 0.f, a3 = 0.f;
#pragma unroll
                for (int m = 0; m < 8; ++m) {
                    a0 = dot2f(ha[m], wi[0][m], a0);
                    a0 = dot2f(hb[m], wh[0][m], a0);
                    a1 = dot2f(ha[m], wi[1][m], a1);
                    a1 = dot2f(hb[m], wh[1][m], a1);
                    a2 = dot2f(ha[m], wi[2][m], a2);
                    a2 = dot2f(hb[m], wh[2][m], a2);
                    a3 = dot2f(ha[m], wi[3][m], a3);
                    a3 = dot2f(hb[m], wh[3][m], a3);
                }
                a0 = wave_sum64_dpp(a0);
                a1 = wave_sum64_dpp(a1);
                a2 = wave_sum64_dpp(a2);
                a3 = wave_sum64_dpp(a3);
                if (s == 63) {
                    float i_ = sigm(a0 + b0), f_ = sigm(a1 + b1);
                    float g_ = fast_tanh(a2 + b2), o_ = sigm(a3 + b3);
                    cs2 = f_ * cs2 + i_ * g_;
                    gb2[q] = o_ * fast_tanh(cs2);
                }
            }
            __syncthreads();                                   // B1
            if (do2 && tid < 8)
                agent_storeu(H2p + (size_t)t * 512 + pbase + tid,
                             pack_h(gb2[2 * tid], gb2[2 * tid + 1]));

            // ---- Phase L3 (visibility of h2 overlaps this work) ----
            if (do3) {
                unsigned hb[8], hc[8];
#pragma unroll
                for (int m = 0; m < 8; ++m) {
                    hb[m] = shp2[s + 64 * m];
                    hc[m] = shp3[s + 64 * m];
                }
                float a0 = 0.f, a1 = 0.f, a2 = 0.f, a3 = 0.f;
#pragma unroll
                for (int m = 0; m < 8; ++m) {
                    a0 = dot2f(hb[m], wi[0][m], a0);
                    a0 = dot2f(hc[m], wh[0][m], a0);
                    a1 = dot2f(hb[m], wi[1][m], a1);
                    a1 = dot2f(hc[m], wh[1][m], a1);
                    a2 = dot2f(hb[m], wi[2][m], a2);
                    a2 = dot2f(hc[m], wh[2][m], a2);
                    a3 = dot2f(hb[m], wi[3][m], a3);
                    a3 = dot2f(hc[m], wh[3][m], a3);
                }
                a0 = wave_sum64_dpp(a0);
                a1 = wave_sum64_dpp(a1);
                a2 = wave_sum64_dpp(a2);
                a3 = wave_sum64_dpp(a3);
                if (s == 63) {
                    float i_ = sigm(a0 + b0), f_ = sigm(a1 + b1);
                    float g_ = fast_tanh(a2 + b2), o_ = sigm(a3 + b3);
                    cs3 = f_ * cs3 + i_ * g_;
                    gb3[q] = o_ * fast_tanh(cs3);
                }
            }
            __syncthreads();                                   // B2
            if (do3) {
                if (tid < 8)
                    agent_storeu(H3p + (size_t)(t - 1) * 512 + pbase + tid,
                                 pack_h(gb3[2 * tid], gb3[2 * tid + 1]));
                if (tid < 16)
                    H3f[(size_t)(t - 1) * HDIM + u0 + tid] = gb3[tid];
            }
        }
    }
}

// ---------------------------------------------------------------------------
// Attention (unchanged, proven; reads fp32 H3f)
// ---------------------------------------------------------------------------
__global__ __launch_bounds__(256) void attn_dot(
    const float* __restrict__ H3, float* __restrict__ attn)
{
    const int t = blockIdx.x * 4 + (threadIdx.x >> 6);
    const int lane = threadIdx.x & 63;
    const float* hrow = H3 + (size_t)t * HDIM;
    const float* hf = H3 + (size_t)(TSTEPS - 1) * HDIM;
    float p = 0.f;
    for (int j = lane; j < HDIM; j += 64) p = fmaf(hrow[j], hf[j], p);
#pragma unroll
    for (int d = 32; d; d >>= 1) p += __shfl_down(p, d, 64);
    if (lane == 0) attn[t] = p;
}

__global__ __launch_bounds__(64) void softmax_1024(float* attn)
{
    const int lane = threadIdx.x;
    float vals[16];
    float m = -1e30f;
#pragma unroll
    for (int i = 0; i < 16; i++) {
        vals[i] = attn[lane + i * 64];
        m = fmaxf(m, vals[i]);
    }
#pragma unroll
    for (int d = 32; d; d >>= 1) m = fmaxf(m, __shfl_xor(m, d, 64));
    float s = 0.f;
#pragma unroll
    for (int i = 0; i < 16; i++) {
        vals[i] = expf(vals[i] - m);
        s += vals[i];
    }
#pragma unroll
    for (int d = 32; d; d >>= 1) s += __shfl_xor(s, d, 64);
    float inv = 1.f / s;
#pragma unroll
    for (int i = 0; i < 16; i++) attn[lane + i * 64] = vals[i] * inv;
}

__global__ __launch_bounds__(256) void context_kernel(
    const float* __restrict__ H3, const float* __restrict__ w,
    float* __restrict__ out)
{
    const int u = blockIdx.x * 4 + (threadIdx.x >> 6);
    const int lane = threadIdx.x & 63;
    float p = 0.f;
    for (int t = lane; t < TSTEPS; t += 64)
        p = fmaf(H3[(size_t)t * HDIM + u], w[t], p);
#pragma unroll
    for (int d = 32; d; d >>= 1) p += __shfl_down(p, d, 64);
    if (lane == 0) out[u] = p;
}

// ---------------------------------------------------------------------------
// Launch
// ---------------------------------------------------------------------------
extern "C" void kernel_launch(void* const* d_in, const int* in_sizes, int n_in,
                              void* d_out, int out_size, void* d_ws, size_t ws_size,
                              hipStream_t stream)
{
    const float* x     = (const float*)d_in[0];
    const float* timev = (const float*)d_in[1];
    const float* h0_1  = (const float*)d_in[2];
    const float* c0_1  = (const float*)d_in[3];
    const float* h0_2  = (const float*)d_in[4];
    const float* c0_2  = (const float*)d_in[5];
    const float* h0_3  = (const float*)d_in[6];
    const float* c0_3  = (const float*)d_in[7];
    const float* Wih1  = (const float*)d_in[8];
    const float* Whh1  = (const float*)d_in[9];
    const float* bih1  = (const float*)d_in[10];
    const float* bhh1  = (const float*)d_in[11];
    const float* Wih2  = (const float*)d_in[12];
    const float* Whh2  = (const float*)d_in[13];
    const float* bih2  = (const float*)d_in[14];
    const float* bhh2  = (const float*)d_in[15];

    // workspace carve (~50 MB)
    float* G      = (float*)d_ws;                         // 1024*4096 fp32
    unsigned* H1p = (unsigned*)(G + (size_t)TSTEPS * NGATE);  // 1024*512 uints
    unsigned* H2p = H1p + (size_t)TSTEPS * 512;
    unsigned* H3p = H2p + (size_t)TSTEPS * 512;
    float* H3f    = (float*)(H3p + (size_t)TSTEPS * 512); // 1024*1024 fp32
    float* attn   = H3f + (size_t)TSTEPS * HDIM;          // 1024 fp32
    unsigned* Wp1  = (unsigned*)(attn + 1024);            // 4096*512 uints each
    unsigned* Wpi2 = Wp1 + (size_t)NGATE * 512;
    unsigned* Wph2 = Wpi2 + (size_t)NGATE * 512;
    float* out  = (float*)d_out;

    // Poison packed H rows (contiguous): the data-poll protocol depends on it.
    hipMemsetAsync(H1p, 0x7C, (size_t)3 * TSTEPS * 512 * sizeof(unsigned), stream);

    // Pack the three scan weight matrices to f16 pairs (one-time).
    {
        const int n = NGATE * 512;
        pack_f16<<<dim3(n / 256), dim3(256), 0, stream>>>(Whh1, Wp1, n);
        pack_f16<<<dim3(n / 256), dim3(256), 0, stream>>>(Wih2, Wpi2, n);
        pack_f16<<<dim3(n / 256), dim3(256), 0, stream>>>(Whh2, Wph2, n);
    }

    // Layer-1 input gates: G = concat(x,time) @ Wih1^T + bih1 + bhh1 (fp32)
    gemm_tn<<<dim3(1024), dim3(256), 0, stream>>>(Wih1, bih1, bhh1, G,
                                                  TSTEPS, NGATE, INDIM + 1, x, timev);

    // Fused dataflow scan (cooperative: 128 WGs x 1024 threads)
    {
        const unsigned* a0 = Wp1;  const float* a1 = G;
        const unsigned* a2 = Wpi2; const unsigned* a3 = Wph2;
        const float* a4 = bih2;  const float* a5 = bhh2;
        const float* a6 = h0_1;  const float* a7 = c0_1;
        const float* a8 = h0_2;  const float* a9 = c0_2;
        const float* a10 = h0_3; const float* a11 = c0_3;
        unsigned* a12 = H1p; unsigned* a13 = H2p; unsigned* a14 = H3p;
        float* a15 = H3f;
        void* args[] = {&a0,&a1,&a2,&a3,&a4,&a5,&a6,&a7,&a8,&a9,&a10,&a11,
                        &a12,&a13,&a14,&a15};
        hipLaunchCooperativeKernel((void*)fused_scan, dim3(NWG_TOT), dim3(1024),
                                   args, 0, stream);
    }

    // Attention
    attn_dot<<<dim3(256), dim3(256), 0, stream>>>(H3f, attn);
    softmax_1024<<<dim3(1), dim3(64), 0, stream>>>(attn);
    context_kernel<<<dim3(256), dim3(256), 0, stream>>>(H3f, attn, out);
}

// Round 7
// 3145.347 us; speedup vs baseline: 1.4904x; 1.4904x over previous
//
#include <hip/hip_runtime.h>
#include <hip/hip_fp16.h>

// Problem constants
#define TSTEPS 1024
#define HDIM   1024
#define INDIM  512
#define NGATE  4096     // 4*HDIM
#define NWG_L1  64
#define NWG_L23 128
#define NWG_TOT 192     // proven coop envelope
#define POISON_U 0x7C7C7C7Cu   // f16-pair poison: halves are f16 NaN; |h|<1 can't make it
#define SPIN_MAX (1 << 20)     // deadlock valve: fail loud, never hang

// ---------------------------------------------------------------------------
// R17 post-mortem: f16 transport halved FETCH as predicted (75MB) but dur
// regressed: VGPR_Count=64 with 64 resident weight uints => spill storm, plus
// serialized L2->L3 and halved occupancy. Lessons: (a) packing works,
// (b) NEVER exceed 32 resident weight uints/thread, (c) keep L2/L3 in
// parallel waves.
// R18 = R16 structure (192 WGs, wave-split L23, 32 resident uints, gbuf +
// coalesced stores) + three targeted grafts:
//   1. f16-packed h transport (512-uint rows): half poll/store payload.
//   2. L23 phase-split staging: h1 staged early (prefetched, has slack);
//      wi*h1 partial dots run BEFORE polling h2[t-1]/h3[t-2] (the zero-slack
//      rows, stored only at the END of the previous iteration) -> their poll
//      starts ~0.3us later in wall-clock and catches in ~1 try.
//   3. Cross-iteration prefetch of the h1 row (issue at end of iter t,
//      check at top of t+1).
// ---------------------------------------------------------------------------

typedef _Float16 half2v __attribute__((ext_vector_type(2)));

#define PINU(v) asm volatile("" : "+v"(v))

// both-operands-packed f16 dot pair -> 2x v_fma_mix (R14/R17-validated)
__device__ __forceinline__ float dot2f(unsigned h, unsigned w, float c) {
    half2v a = __builtin_bit_cast(half2v, h);
    half2v b = __builtin_bit_cast(half2v, w);
    c = fmaf((float)a[0], (float)b[0], c);
    c = fmaf((float)a[1], (float)b[1], c);
    return c;
}

// Full-wave sum via DPP adds (VALU pipe; validated R14-R17). Result valid in
// lane 63. row_shr 1,2,4,8 then row_bcast15 (rows 1,3) + row_bcast31 (rows 2,3).
__device__ __forceinline__ float wave_sum64_dpp(float v) {
    int x;
    x = __builtin_amdgcn_update_dpp(0, __float_as_int(v), 0x111, 0xf, 0xf, false); v += __int_as_float(x);
    x = __builtin_amdgcn_update_dpp(0, __float_as_int(v), 0x112, 0xf, 0xf, false); v += __int_as_float(x);
    x = __builtin_amdgcn_update_dpp(0, __float_as_int(v), 0x114, 0xf, 0xf, false); v += __int_as_float(x);
    x = __builtin_amdgcn_update_dpp(0, __float_as_int(v), 0x118, 0xf, 0xf, false); v += __int_as_float(x);
    x = __builtin_amdgcn_update_dpp(0, __float_as_int(v), 0x142, 0xa, 0xf, false); v += __int_as_float(x);
    x = __builtin_amdgcn_update_dpp(0, __float_as_int(v), 0x143, 0xc, 0xf, false); v += __int_as_float(x);
    return v;
}

__device__ __forceinline__ float sigm(float x) { return 1.f / (1.f + __expf(-x)); }
__device__ __forceinline__ float fast_tanh(float x) {
    float t = __expf(-2.f * fabsf(x));
    float r = (1.f - t) / (1.f + t);
    return copysignf(r, x);
}

// single-instruction f32 pair -> packed f16 (v_cvt_pkrtz_f16_f32)
__device__ __forceinline__ unsigned pack_h(float a, float b) {
    auto p = __builtin_amdgcn_cvt_pkrtz(a, b);
    return __builtin_bit_cast(unsigned, p);
}

__device__ __forceinline__ unsigned agent_loadu(const unsigned* p) {
    return __hip_atomic_load(const_cast<unsigned*>(p), __ATOMIC_RELAXED,
                             __HIP_MEMORY_SCOPE_AGENT);
}
__device__ __forceinline__ void agent_storeu(unsigned* p, unsigned v) {
    __hip_atomic_store(p, v, __ATOMIC_RELAXED, __HIP_MEMORY_SCOPE_AGENT);
}

// ---------------------------------------------------------------------------
// Prep: pack fp32 matrix (rows x 1024) into f16-pair uints (rows x 512), RNE.
// ---------------------------------------------------------------------------
__global__ __launch_bounds__(256) void pack_f16(
    const float* __restrict__ src, unsigned* __restrict__ dst, int n)
{
    int i = blockIdx.x * 256 + threadIdx.x;
    if (i < n) {
        float2 v = *(const float2*)(src + 2 * (size_t)i);
        dst[i] = (unsigned)__half_as_ushort(__float2half(v.x)) |
                 ((unsigned)__half_as_ushort(__float2half(v.y)) << 16);
    }
}

// ---------------------------------------------------------------------------
// GEMM for layer-1 input gates (fp32, one-shot — unchanged, proven)
// ---------------------------------------------------------------------------
#define BM 64
#define BN 64
#define BK 32

__global__ __launch_bounds__(256) void gemm_tn(
    const float* __restrict__ B,
    const float* __restrict__ bias1,
    const float* __restrict__ bias2,
    float* __restrict__ C,
    int M, int N, int K,
    const float* __restrict__ x,
    const float* __restrict__ timev)
{
    __shared__ float As[BK][BM + 4];
    __shared__ float Bs[BK][BN + 4];

    const int tid = threadIdx.x;
    const int mblocks = M / BM;
    const int bm = blockIdx.x % mblocks;
    const int bn = blockIdx.x / mblocks;
    const int t0 = bm * BM;
    const int n0 = bn * BN;

    const int tx = tid & 15;
    const int ty = tid >> 4;

    float acc[4][4] = {{0.f}};

    for (int kc = 0; kc < K; kc += BK) {
#pragma unroll
        for (int i = 0; i < 8; i++) {
            int idx = tid + i * 256;
            int r = idx >> 5;
            int c = idx & 31;
            int col = kc + c;
            int trow = t0 + r;
            float av = (col < INDIM) ? x[(size_t)trow * INDIM + col]
                                     : ((col == INDIM) ? timev[trow] : 0.f);
            As[c][r] = av;
            int nrow = n0 + r;
            Bs[c][r] = (col < K) ? B[(size_t)nrow * K + col] : 0.f;
        }
        __syncthreads();

#pragma unroll
        for (int kk = 0; kk < BK; kk++) {
            float a[4], b[4];
#pragma unroll
            for (int i = 0; i < 4; i++) a[i] = As[kk][ty * 4 + i];
#pragma unroll
            for (int j = 0; j < 4; j++) b[j] = Bs[kk][tx * 4 + j];
#pragma unroll
            for (int i = 0; i < 4; i++)
#pragma unroll
                for (int j = 0; j < 4; j++)
                    acc[i][j] = fmaf(a[i], b[j], acc[i][j]);
        }
        __syncthreads();
    }

#pragma unroll
    for (int i = 0; i < 4; i++) {
        int trow = t0 + ty * 4 + i;
#pragma unroll
        for (int j = 0; j < 4; j++) {
            int n = n0 + tx * 4 + j;
            C[(size_t)trow * N + n] = acc[i][j] + bias1[n] + bias2[n];
        }
    }
}

// ---------------------------------------------------------------------------
// Fused dataflow 3-layer scan (R16 structure + packed transport + phase split).
// H rows: packed f16 pairs, 512 uints/row. Weight uint j = cols (2j,2j+1);
// lane s handles uint indices s+64m, m=0..7 -> LDS reads shp[s+64m].
// L1 (wg<64): 16 units/WG, wave q owns unit u0+q (all 4 gates, 32 uints).
// L23 (wg>=64): 8 units/WG, wave q owns unit u0+(q>>1), gate pair q&1, for
//   BOTH L2 and L3 (shared wi/wh, 32 uints resident).
// ---------------------------------------------------------------------------
__global__ __launch_bounds__(1024, 4) void fused_scan(
    const unsigned* __restrict__ Wp1,     // packed Whh1, 4096 x 512
    const float* __restrict__ G1,
    const unsigned* __restrict__ Wpi2,    // packed Wih2
    const unsigned* __restrict__ Wph2,    // packed Whh2
    const float* bih2, const float* bhh2,
    const float* h0_1, const float* c0_1,
    const float* h0_2, const float* c0_2,
    const float* h0_3, const float* c0_3,
    unsigned* H1p, unsigned* H2p, unsigned* H3p,  // packed h rows, poisoned
    float* H3f)                                   // fp32 h3 for attention
{
    __shared__ unsigned shp1[512];
    __shared__ unsigned shp2[512];
    __shared__ unsigned shp3[512];
    __shared__ float gbuf[16][4];  // L1: [unit][gate]; L23: 0-7 L2, 8-15 L3

    const int tid = threadIdx.x;
    const int wg  = blockIdx.x;
    const int q   = tid >> 6;      // wave 0..15
    const int s   = tid & 63;

    if (wg < NWG_L1) {
        // ------- Layer 1: WG owns 16 units, wave q owns unit u0+q -------
        const int u0 = wg << 4;
        const int u  = u0 + q;
        unsigned w[4][8];
#pragma unroll
        for (int g = 0; g < 4; ++g) {
            const unsigned* row = Wp1 + (size_t)((g << 10) + u) * 512 + s;
#pragma unroll
            for (int m = 0; m < 8; ++m)
                w[g][m] = row[64 * m];
        }
        float c1 = (tid < 16) ? c0_1[u0 + tid] : 0.f;
        unsigned pv = 0u;   // cross-iteration prefetch of the h1 row

        for (int t = 0; t < TSTEPS; ++t) {
#pragma unroll
            for (int g = 0; g < 4; ++g)
#pragma unroll
                for (int m = 0; m < 8; ++m) PINU(w[g][m]);

            float Gv0 = 0.f, Gv1 = 0.f, Gv2 = 0.f, Gv3 = 0.f;
            if (tid < 16) {   // prefetch gate inputs (normal cached loads)
                const float* gptr = G1 + (size_t)t * NGATE + u0 + tid;
                Gv0 = gptr[0];
                Gv1 = gptr[1024];
                Gv2 = gptr[2048];
                Gv3 = gptr[3072];
            }
            // stage packed h1[t-1]: check prefetched value, spin-fix misses
            if (tid < 512) {
                if (t == 0) {
                    shp1[tid] = pack_h(h0_1[2 * tid], h0_1[2 * tid + 1]);
                } else {
                    const unsigned* p = H1p + (size_t)(t - 1) * 512 + tid;
                    unsigned v = pv;
                    for (int it = 0; it < SPIN_MAX; ++it) {
                        if (__ballot(v == POISON_U) == 0ULL) break;
                        __builtin_amdgcn_s_sleep(1);
                        if (v == POISON_U) v = agent_loadu(p);
                    }
                    shp1[tid] = v;
                }
            }
            __syncthreads();                                   // A: staged

            float a0 = 0.f, a1 = 0.f, a2 = 0.f, a3 = 0.f;
#pragma unroll
            for (int m = 0; m < 8; ++m) {
                unsigned hu = shp1[s + 64 * m];
                a0 = dot2f(hu, w[0][m], a0);
                a1 = dot2f(hu, w[1][m], a1);
                a2 = dot2f(hu, w[2][m], a2);
                a3 = dot2f(hu, w[3][m], a3);
            }
            a0 = wave_sum64_dpp(a0);
            a1 = wave_sum64_dpp(a1);
            a2 = wave_sum64_dpp(a2);
            a3 = wave_sum64_dpp(a3);
            if (s == 63) {
                gbuf[q][0] = a0;
                gbuf[q][1] = a1;
                gbuf[q][2] = a2;
                gbuf[q][3] = a3;
            }
            __syncthreads();                                   // B: sums ready

            if (tid < 16) {
                float gi = gbuf[tid][0] + Gv0;
                float gf = gbuf[tid][1] + Gv1;
                float gg = gbuf[tid][2] + Gv2;
                float go = gbuf[tid][3] + Gv3;
                float i_ = sigm(gi), f_ = sigm(gf), g_ = fast_tanh(gg), o_ = sigm(go);
                c1 = f_ * c1 + i_ * g_;
                float hn = o_ * fast_tanh(c1);
                float hnn = __shfl_down(hn, 1, 64);
                if (!(tid & 1))
                    agent_storeu(H1p + (size_t)t * 512 + (u0 >> 1) + (tid >> 1),
                                 pack_h(hn, hnn));
            }
            // cross-iteration prefetch: issue load of the row just produced
            if (tid < 512 && t < TSTEPS - 1) {
                pv = agent_loadu(H1p + (size_t)t * 512 + tid);
                PINU(pv);
            }
        }
    } else {
        // ---- Layers 2 & 3 (shared weights): WG owns 8 units ----
        const int ul = q >> 1;     // unit-local 0..7
        const int gp = q & 1;      // 0 -> gates (i,f), 1 -> gates (g,o)
        const int u0 = (wg - NWG_L1) << 3;
        const int u  = u0 + ul;
        unsigned wi[2][8], wh[2][8];
#pragma unroll
        for (int j = 0; j < 2; ++j) {
            const unsigned* ri = Wpi2 + (size_t)(((2 * gp + j) << 10) + u) * 512 + s;
            const unsigned* rh = Wph2 + (size_t)(((2 * gp + j) << 10) + u) * 512 + s;
#pragma unroll
            for (int m = 0; m < 8; ++m) {
                wi[j][m] = ri[64 * m];
                wh[j][m] = rh[64 * m];
            }
        }
        float bias0 = 0.f, bias1v = 0.f, bias2v = 0.f, bias3 = 0.f, cst = 0.f;
        if (tid < 16) {
            int uu = u0 + (tid & 7);
            bias0  = bih2[uu]        + bhh2[uu];
            bias1v = bih2[1024 + uu] + bhh2[1024 + uu];
            bias2v = bih2[2048 + uu] + bhh2[2048 + uu];
            bias3  = bih2[3072 + uu] + bhh2[3072 + uu];
            cst = (tid < 8) ? c0_2[u0 + tid] : c0_3[u0 + tid - 8];
        }
        unsigned pv1 = 0u;  // cross-iteration prefetch of h1 row
        if (tid < 512) pv1 = agent_loadu(H1p + tid);   // prologue: row 0

        // iteration t: layer2 tick t (needs h1[t], h2[t-1]) and
        //              layer3 tick t-1 (needs h2[t-1], h3[t-2])
        for (int t = 0; t <= TSTEPS; ++t) {
#pragma unroll
            for (int j = 0; j < 2; ++j)
#pragma unroll
                for (int m = 0; m < 8; ++m) { PINU(wi[j][m]); PINU(wh[j][m]); }

            const bool do2 = (t < TSTEPS);
            const bool do3 = (t >= 1);

            // ---- phase 0: stage h1[t] (slack row, prefetched) ----
            if (tid < 512 && do2) {
                const unsigned* p = H1p + (size_t)t * 512 + tid;
                unsigned v = pv1;
                for (int it = 0; it < SPIN_MAX; ++it) {
                    if (__ballot(v == POISON_U) == 0ULL) break;
                    __builtin_amdgcn_s_sleep(1);
                    if (v == POISON_U) v = agent_loadu(p);
                }
                shp1[tid] = v;
            }
            __syncthreads();                                   // A1: h1 staged

            // ---- phase 1: wi*h1 partial dots (overlaps peers' h2/h3 stores)
            float p20 = 0.f, p21 = 0.f;
#pragma unroll
            for (int m = 0; m < 8; ++m) {
                unsigned h1u = shp1[s + 64 * m];
                p20 = dot2f(h1u, wi[0][m], p20);
                p21 = dot2f(h1u, wi[1][m], p21);
            }

            // ---- phase 2: NOW poll the zero-slack rows h2[t-1], h3[t-2] ----
            if (tid < 512) {
                if (t == 0) {
                    shp2[tid] = pack_h(h0_2[2 * tid], h0_2[2 * tid + 1]);
                } else {
                    const unsigned* p = H2p + (size_t)(t - 1) * 512 + tid;
                    unsigned v = agent_loadu(p);
                    for (int it = 0; it < SPIN_MAX; ++it) {
                        if (__ballot(v == POISON_U) == 0ULL) break;
                        __builtin_amdgcn_s_sleep(1);
                        if (v == POISON_U) v = agent_loadu(p);
                    }
                    shp2[tid] = v;
                }
            } else {
                const int sid = tid - 512;
                if (t == 1) {
                    shp3[sid] = pack_h(h0_3[2 * sid], h0_3[2 * sid + 1]);
                } else if (t > 1) {
                    const unsigned* p = H3p + (size_t)(t - 2) * 512 + sid;
                    unsigned v = agent_loadu(p);
                    for (int it = 0; it < SPIN_MAX; ++it) {
                        if (__ballot(v == POISON_U) == 0ULL) break;
                        __builtin_amdgcn_s_sleep(1);
                        if (v == POISON_U) v = agent_loadu(p);
                    }
                    shp3[sid] = v;
                }
            }
            __syncthreads();                                   // A2: h2/h3 staged

            // ---- phase 3: remaining dots ----
            float p30 = 0.f, p31 = 0.f;
#pragma unroll
            for (int m = 0; m < 8; ++m) {
                unsigned h2u = shp2[s + 64 * m];
                unsigned h3u = shp3[s + 64 * m];
                p20 = dot2f(h2u, wh[0][m], p20);
                p21 = dot2f(h2u, wh[1][m], p21);
                p30 = dot2f(h2u, wi[0][m], p30);
                p31 = dot2f(h2u, wi[1][m], p31);
                p30 = dot2f(h3u, wh[0][m], p30);
                p31 = dot2f(h3u, wh[1][m], p31);
            }
            float s20 = wave_sum64_dpp(p20);
            float s21 = wave_sum64_dpp(p21);
            float s30 = wave_sum64_dpp(p30);
            float s31 = wave_sum64_dpp(p31);
            if (s == 63) {
                gbuf[ul][2 * gp]          = s20;
                gbuf[ul][2 * gp + 1]      = s21;
                gbuf[8 + ul][2 * gp]      = s30;
                gbuf[8 + ul][2 * gp + 1]  = s31;
            }
            __syncthreads();                                   // B: sums ready

            if (tid < 16) {
                const bool act = (tid < 8) ? do2 : do3;
                float hn = 0.f;
                if (act) {
                    float gi = gbuf[tid][0] + bias0;
                    float gf = gbuf[tid][1] + bias1v;
                    float gg = gbuf[tid][2] + bias2v;
                    float go = gbuf[tid][3] + bias3;
                    float i_ = sigm(gi), f_ = sigm(gf), g_ = fast_tanh(gg), o_ = sigm(go);
                    cst = f_ * cst + i_ * g_;
                    hn = o_ * fast_tanh(cst);
                }
                float hnn = __shfl_down(hn, 1, 64);
                if (act) {
                    if (tid < 8) {         // h2 units: packed store (4 uints/WG)
                        if (!(tid & 1))
                            agent_storeu(H2p + (size_t)t * 512 + (u0 >> 1) + (tid >> 1),
                                         pack_h(hn, hnn));
                    } else {               // h3 units: packed + fp32 for attn
                        if (!(tid & 1))
                            agent_storeu(H3p + (size_t)(t - 1) * 512 + (u0 >> 1) + ((tid - 8) >> 1),
                                         pack_h(hn, hnn));
                        H3f[(size_t)(t - 1) * HDIM + u0 + (tid - 8)] = hn;
                    }
                }
            }
            // cross-iteration prefetch of h1[t+1]
            if (tid < 512 && t < TSTEPS - 1) {
                pv1 = agent_loadu(H1p + (size_t)(t + 1) * 512 + tid);
                PINU(pv1);
            }
        }
    }
}

// ---------------------------------------------------------------------------
// Attention (unchanged, proven; reads fp32 H3f)
// ---------------------------------------------------------------------------
__global__ __launch_bounds__(256) void attn_dot(
    const float* __restrict__ H3, float* __restrict__ attn)
{
    const int t = blockIdx.x * 4 + (threadIdx.x >> 6);
    const int lane = threadIdx.x & 63;
    const float* hrow = H3 + (size_t)t * HDIM;
    const float* hf = H3 + (size_t)(TSTEPS - 1) * HDIM;
    float p = 0.f;
    for (int j = lane; j < HDIM; j += 64) p = fmaf(hrow[j], hf[j], p);
#pragma unroll
    for (int d = 32; d; d >>= 1) p += __shfl_down(p, d, 64);
    if (lane == 0) attn[t] = p;
}

__global__ __launch_bounds__(64) void softmax_1024(float* attn)
{
    const int lane = threadIdx.x;
    float vals[16];
    float m = -1e30f;
#pragma unroll
    for (int i = 0; i < 16; i++) {
        vals[i] = attn[lane + i * 64];
        m = fmaxf(m, vals[i]);
    }
#pragma unroll
    for (int d = 32; d; d >>= 1) m = fmaxf(m, __shfl_xor(m, d, 64));
    float s = 0.f;
#pragma unroll
    for (int i = 0; i < 16; i++) {
        vals[i] = expf(vals[i] - m);
        s += vals[i];
    }
#pragma unroll
    for (int d = 32; d; d >>= 1) s += __shfl_xor(s, d, 64);
    float inv = 1.f / s;
#pragma unroll
    for (int i = 0; i < 16; i++) attn[lane + i * 64] = vals[i] * inv;
}

__global__ __launch_bounds__(256) void context_kernel(
    const float* __restrict__ H3, const float* __restrict__ w,
    float* __restrict__ out)
{
    const int u = blockIdx.x * 4 + (threadIdx.x >> 6);
    const int lane = threadIdx.x & 63;
    float p = 0.f;
    for (int t = lane; t < TSTEPS; t += 64)
        p = fmaf(H3[(size_t)t * HDIM + u], w[t], p);
#pragma unroll
    for (int d = 32; d; d >>= 1) p += __shfl_down(p, d, 64);
    if (lane == 0) out[u] = p;
}

// ---------------------------------------------------------------------------
// Launch
// ---------------------------------------------------------------------------
extern "C" void kernel_launch(void* const* d_in, const int* in_sizes, int n_in,
                              void* d_out, int out_size, void* d_ws, size_t ws_size,
                              hipStream_t stream)
{
    const float* x     = (const float*)d_in[0];
    const float* timev = (const float*)d_in[1];
    const float* h0_1  = (const float*)d_in[2];
    const float* c0_1  = (const float*)d_in[3];
    const float* h0_2  = (const float*)d_in[4];
    const float* c0_2  = (const float*)d_in[5];
    const float* h0_3  = (const float*)d_in[6];
    const float* c0_3  = (const float*)d_in[7];
    const float* Wih1  = (const float*)d_in[8];
    const float* Whh1  = (const float*)d_in[9];
    const float* bih1  = (const float*)d_in[10];
    const float* bhh1  = (const float*)d_in[11];
    const float* Wih2  = (const float*)d_in[12];
    const float* Whh2  = (const float*)d_in[13];
    const float* bih2  = (const float*)d_in[14];
    const float* bhh2  = (const float*)d_in[15];

    // workspace carve (~50 MB)
    float* G      = (float*)d_ws;                             // 1024*4096 fp32
    unsigned* H1p = (unsigned*)(G + (size_t)TSTEPS * NGATE);  // 1024*512 uints
    unsigned* H2p = H1p + (size_t)TSTEPS * 512;
    unsigned* H3p = H2p + (size_t)TSTEPS * 512;
    float* H3f    = (float*)(H3p + (size_t)TSTEPS * 512);     // 1024*1024 fp32
    float* attn   = H3f + (size_t)TSTEPS * HDIM;              // 1024 fp32
    unsigned* Wp1  = (unsigned*)(attn + 1024);                // 4096*512 uints each
    unsigned* Wpi2 = Wp1 + (size_t)NGATE * 512;
    unsigned* Wph2 = Wpi2 + (size_t)NGATE * 512;
    float* out  = (float*)d_out;

    // Poison packed H rows (contiguous): the data-poll protocol depends on it.
    hipMemsetAsync(H1p, 0x7C, (size_t)3 * TSTEPS * 512 * sizeof(unsigned), stream);

    // Pack the three scan weight matrices to f16 pairs (one-time).
    {
        const int n = NGATE * 512;
        pack_f16<<<dim3(n / 256), dim3(256), 0, stream>>>(Whh1, Wp1, n);
        pack_f16<<<dim3(n / 256), dim3(256), 0, stream>>>(Wih2, Wpi2, n);
        pack_f16<<<dim3(n / 256), dim3(256), 0, stream>>>(Whh2, Wph2, n);
    }

    // Layer-1 input gates: G = concat(x,time) @ Wih1^T + bih1 + bhh1 (fp32)
    gemm_tn<<<dim3(1024), dim3(256), 0, stream>>>(Wih1, bih1, bhh1, G,
                                                  TSTEPS, NGATE, INDIM + 1, x, timev);

    // Fused dataflow scan (cooperative: 192 WGs x 1024 threads)
    {
        const unsigned* a0 = Wp1;  const float* a1 = G;
        const unsigned* a2 = Wpi2; const unsigned* a3 = Wph2;
        const float* a4 = bih2;  const float* a5 = bhh2;
        const float* a6 = h0_1;  const float* a7 = c0_1;
        const float* a8 = h0_2;  const float* a9 = c0_2;
        const float* a10 = h0_3; const float* a11 = c0_3;
        unsigned* a12 = H1p; unsigned* a13 = H2p; unsigned* a14 = H3p;
        float* a15 = H3f;
        void* args[] = {&a0,&a1,&a2,&a3,&a4,&a5,&a6,&a7,&a8,&a9,&a10,&a11,
                        &a12,&a13,&a14,&a15};
        hipLaunchCooperativeKernel((void*)fused_scan, dim3(NWG_TOT), dim3(1024),
                                   args, 0, stream);
    }

    // Attention
    attn_dot<<<dim3(256), dim3(256), 0, stream>>>(H3f, attn);
    softmax_1024<<<dim3(1), dim3(64), 0, stream>>>(attn);
    context_kernel<<<dim3(256), dim3(256), 0, stream>>>(H3f, attn, out);
}

// Round 8
// 2784.476 us; speedup vs baseline: 1.6835x; 1.1296x over previous
//
#include <hip/hip_runtime.h>
#include <hip/hip_fp16.h>

// Problem constants
#define TSTEPS 1024
#define HDIM   1024
#define INDIM  512
#define NGATE  4096     // 4*HDIM
#define NWG_L1  64
#define NWG_L23 128
#define NWG_TOT 192     // proven coop envelope
#define POISON_U 0x7C7C7C7Cu   // f16-pair poison; as f32 = 5.2e36 (unreachable)
#define SPIN_MAX (1 << 20)     // deadlock valve: fail loud, never hang

// ---------------------------------------------------------------------------
// R18 post-mortem: 3145us best; FETCH 69MB => poll traffic now LLC-absorbed;
// cadence 2.93us/step = agent-scope store->visible RT + straggler max on the
// self-recurrent rows (L1's h1 cycle is the tightest). VALUBusy 39%.
// R19 (additive, protocol unchanged):
//  1. G-GEMM moved INSIDE fused_scan (L23 WGs, 4x256-thread teams, 2 tiles
//     each -> aligned WG barriers; agent stores; G poisoned; L1 polls G and
//     validates at activation). L1 free-runs ~2.9us/step and needs G[t] only
//     at step t -> the whole ~100us GEMM + launch gap hide in L1's shadow.
//  2. fdot2 (v_dot2_f32_f16) halves dot instruction count (guarded by
//     __has_builtin; operand type via decltype(cvt_pkrtz) - R13 lesson).
// ---------------------------------------------------------------------------

typedef _Float16 half2v __attribute__((ext_vector_type(2)));
typedef decltype(__builtin_amdgcn_cvt_pkrtz(0.f, 0.f)) f16x2b;  // builtin-native v2f16

#define PINU(v) asm volatile("" : "+v"(v))

#if defined(__has_builtin)
#if __has_builtin(__builtin_amdgcn_fdot2)
#define HAVE_FDOT2 1
#endif
#endif

#ifdef HAVE_FDOT2
// one v_dot2_f32_f16 per packed pair (fp32 accumulate)
__device__ __forceinline__ float dot2f(unsigned h, unsigned w, float c) {
    return __builtin_amdgcn_fdot2(__builtin_bit_cast(f16x2b, h),
                                  __builtin_bit_cast(f16x2b, w), c, false);
}
#else
// fallback: 2x v_fma_mix (R14-R18 validated)
__device__ __forceinline__ float dot2f(unsigned h, unsigned w, float c) {
    half2v a = __builtin_bit_cast(half2v, h);
    half2v b = __builtin_bit_cast(half2v, w);
    c = fmaf((float)a[0], (float)b[0], c);
    c = fmaf((float)a[1], (float)b[1], c);
    return c;
}
#endif

// Full-wave sum via DPP adds (VALU pipe; validated R14-R18). Result in lane 63.
__device__ __forceinline__ float wave_sum64_dpp(float v) {
    int x;
    x = __builtin_amdgcn_update_dpp(0, __float_as_int(v), 0x111, 0xf, 0xf, false); v += __int_as_float(x);
    x = __builtin_amdgcn_update_dpp(0, __float_as_int(v), 0x112, 0xf, 0xf, false); v += __int_as_float(x);
    x = __builtin_amdgcn_update_dpp(0, __float_as_int(v), 0x114, 0xf, 0xf, false); v += __int_as_float(x);
    x = __builtin_amdgcn_update_dpp(0, __float_as_int(v), 0x118, 0xf, 0xf, false); v += __int_as_float(x);
    x = __builtin_amdgcn_update_dpp(0, __float_as_int(v), 0x142, 0xa, 0xf, false); v += __int_as_float(x);
    x = __builtin_amdgcn_update_dpp(0, __float_as_int(v), 0x143, 0xc, 0xf, false); v += __int_as_float(x);
    return v;
}

__device__ __forceinline__ float sigm(float x) { return 1.f / (1.f + __expf(-x)); }
__device__ __forceinline__ float fast_tanh(float x) {
    float t = __expf(-2.f * fabsf(x));
    float r = (1.f - t) / (1.f + t);
    return copysignf(r, x);
}

__device__ __forceinline__ unsigned pack_h(float a, float b) {
    auto p = __builtin_amdgcn_cvt_pkrtz(a, b);
    return __builtin_bit_cast(unsigned, p);
}

__device__ __forceinline__ unsigned agent_loadu(const unsigned* p) {
    return __hip_atomic_load(const_cast<unsigned*>(p), __ATOMIC_RELAXED,
                             __HIP_MEMORY_SCOPE_AGENT);
}
__device__ __forceinline__ void agent_storeu(unsigned* p, unsigned v) {
    __hip_atomic_store(p, v, __ATOMIC_RELAXED, __HIP_MEMORY_SCOPE_AGENT);
}
__device__ __forceinline__ float agent_loadf(const float* p) {
    return __hip_atomic_load(const_cast<float*>(p), __ATOMIC_RELAXED,
                             __HIP_MEMORY_SCOPE_AGENT);
}
__device__ __forceinline__ void agent_storef(float* p, float v) {
    __hip_atomic_store(p, v, __ATOMIC_RELAXED, __HIP_MEMORY_SCOPE_AGENT);
}
__device__ __forceinline__ bool isp(float v) { return __float_as_uint(v) == POISON_U; }

// ---------------------------------------------------------------------------
// Prep: pack fp32 matrix (rows x 1024) into f16-pair uints (rows x 512), RNE.
// ---------------------------------------------------------------------------
__global__ __launch_bounds__(256) void pack_f16(
    const float* __restrict__ src, unsigned* __restrict__ dst, int n)
{
    int i = blockIdx.x * 256 + threadIdx.x;
    if (i < n) {
        float2 v = *(const float2*)(src + 2 * (size_t)i);
        dst[i] = (unsigned)__half_as_ushort(__float2half(v.x)) |
                 ((unsigned)__half_as_ushort(__float2half(v.y)) << 16);
    }
}

// ---------------------------------------------------------------------------
// In-kernel GEMM tile (256-thread team): G[t0..t0+63][n0..n0+63] =
// concat(x,time)[t] . Wih1[n] + bih1[n] + bhh1[n].  Agent-scope stores.
// NOTE: fixed iteration counts -> WG barrier alignment across 4 teams.
// ---------------------------------------------------------------------------
#define BM 64
#define BN 64
#define BK 32
#define GK (INDIM + 1)   // 513

__device__ __forceinline__ void gemm_tile(
    int bm, int bn, int ttid,
    const float* __restrict__ B, const float* __restrict__ bias1,
    const float* __restrict__ bias2, float* C,
    const float* __restrict__ x, const float* __restrict__ timev,
    float (*As)[BM + 4], float (*Bs)[BN + 4])
{
    const int t0 = bm * BM;
    const int n0 = bn * BN;
    const int tx = ttid & 15;
    const int ty = ttid >> 4;

    float acc[4][4] = {{0.f}};

    for (int kc = 0; kc < GK; kc += BK) {
#pragma unroll
        for (int i = 0; i < 8; i++) {
            int idx = ttid + i * 256;
            int r = idx >> 5;
            int c = idx & 31;
            int col = kc + c;
            int trow = t0 + r;
            float av = (col < INDIM) ? x[(size_t)trow * INDIM + col]
                                     : ((col == INDIM) ? timev[trow] : 0.f);
            As[c][r] = av;
            int nrow = n0 + r;
            Bs[c][r] = (col < GK) ? B[(size_t)nrow * GK + col] : 0.f;
        }
        __syncthreads();

#pragma unroll
        for (int kk = 0; kk < BK; kk++) {
            float a[4], b[4];
#pragma unroll
            for (int i = 0; i < 4; i++) a[i] = As[kk][ty * 4 + i];
#pragma unroll
            for (int j = 0; j < 4; j++) b[j] = Bs[kk][tx * 4 + j];
#pragma unroll
            for (int i = 0; i < 4; i++)
#pragma unroll
                for (int j = 0; j < 4; j++)
                    acc[i][j] = fmaf(a[i], b[j], acc[i][j]);
        }
        __syncthreads();
    }

#pragma unroll
    for (int i = 0; i < 4; i++) {
        int trow = t0 + ty * 4 + i;
#pragma unroll
        for (int j = 0; j < 4; j++) {
            int n = n0 + tx * 4 + j;
            agent_storef(C + (size_t)trow * NGATE + n,
                         acc[i][j] + bias1[n] + bias2[n]);
        }
    }
}

// ---------------------------------------------------------------------------
// Fused dataflow 3-layer scan (R18 structure) + in-kernel G-GEMM (L23 WGs).
// H rows: packed f16 pairs, 512 uints/row. Weight uint j = cols (2j,2j+1);
// lane s handles uint indices s+64m, m=0..7 -> LDS reads shp[s+64m].
// L1 (wg<64): 16 units/WG, wave q owns unit u0+q (all 4 gates, 32 uints);
//   G rows are POLLED (produced in-kernel by L23's GEMM phase).
// L23 (wg>=64): GEMM phase first (4 teams x 2 tiles, t-major order), then
//   scan: 8 units/WG, wave q owns unit u0+(q>>1), gate pair q&1, both layers.
// ---------------------------------------------------------------------------
__global__ __launch_bounds__(1024, 4) void fused_scan(
    const unsigned* __restrict__ Wp1,     // packed Whh1, 4096 x 512
    float* G1,                            // fp32 gate inputs (poisoned; GEMM'd here)
    const unsigned* __restrict__ Wpi2,    // packed Wih2
    const unsigned* __restrict__ Wph2,    // packed Whh2
    const float* __restrict__ Wih1,       // fp32 Wih1 (GEMM operand)
    const float* __restrict__ bih1, const float* __restrict__ bhh1,
    const float* __restrict__ xin, const float* __restrict__ timev,
    const float* bih2, const float* bhh2,
    const float* h0_1, const float* c0_1,
    const float* h0_2, const float* c0_2,
    const float* h0_3, const float* c0_3,
    unsigned* H1p, unsigned* H2p, unsigned* H3p,  // packed h rows, poisoned
    float* H3f)                                   // fp32 h3 for attention
{
    __shared__ unsigned shp1[512];
    __shared__ unsigned shp2[512];
    __shared__ unsigned shp3[512];
    __shared__ float gbuf[16][4];  // L1: [unit][gate]; L23: 0-7 L2, 8-15 L3
    __shared__ float AsT[4][BK][BM + 4];   // GEMM team buffers (L23, phase 0)
    __shared__ float BsT[4][BK][BN + 4];

    const int tid = threadIdx.x;
    const int wg  = blockIdx.x;
    const int q   = tid >> 6;      // wave 0..15
    const int s   = tid & 63;

    if (wg < NWG_L1) {
        // ------- Layer 1: WG owns 16 units, wave q owns unit u0+q -------
        const int u0 = wg << 4;
        const int u  = u0 + q;
        unsigned w[4][8];
#pragma unroll
        for (int g = 0; g < 4; ++g) {
            const unsigned* row = Wp1 + (size_t)((g << 10) + u) * 512 + s;
#pragma unroll
            for (int m = 0; m < 8; ++m)
                w[g][m] = row[64 * m];
        }
        float c1 = (tid < 16) ? c0_1[u0 + tid] : 0.f;
        unsigned pv = 0u;   // cross-iteration prefetch of the h1 row

        for (int t = 0; t < TSTEPS; ++t) {
#pragma unroll
            for (int g = 0; g < 4; ++g)
#pragma unroll
                for (int m = 0; m < 8; ++m) PINU(w[g][m]);

            float Gv0 = 0.f, Gv1 = 0.f, Gv2 = 0.f, Gv3 = 0.f;
            if (tid < 16) {   // prefetch gate inputs (agent: in-kernel producer)
                const float* gptr = G1 + (size_t)t * NGATE + u0 + tid;
                Gv0 = agent_loadf(gptr);
                Gv1 = agent_loadf(gptr + 1024);
                Gv2 = agent_loadf(gptr + 2048);
                Gv3 = agent_loadf(gptr + 3072);
            }
            // stage packed h1[t-1]: check prefetched value, spin-fix misses
            if (tid < 512) {
                if (t == 0) {
                    shp1[tid] = pack_h(h0_1[2 * tid], h0_1[2 * tid + 1]);
                } else {
                    const unsigned* p = H1p + (size_t)(t - 1) * 512 + tid;
                    unsigned v = pv;
                    for (int it = 0; it < SPIN_MAX; ++it) {
                        if (__ballot(v == POISON_U) == 0ULL) break;
                        __builtin_amdgcn_s_sleep(1);
                        if (v == POISON_U) v = agent_loadu(p);
                    }
                    shp1[tid] = v;
                }
            }
            __syncthreads();                                   // A: staged

            float a0 = 0.f, a1 = 0.f, a2 = 0.f, a3 = 0.f;
#pragma unroll
            for (int m = 0; m < 8; ++m) {
                unsigned hu = shp1[s + 64 * m];
                a0 = dot2f(hu, w[0][m], a0);
                a1 = dot2f(hu, w[1][m], a1);
                a2 = dot2f(hu, w[2][m], a2);
                a3 = dot2f(hu, w[3][m], a3);
            }
            a0 = wave_sum64_dpp(a0);
            a1 = wave_sum64_dpp(a1);
            a2 = wave_sum64_dpp(a2);
            a3 = wave_sum64_dpp(a3);
            if (s == 63) {
                gbuf[q][0] = a0;
                gbuf[q][1] = a1;
                gbuf[q][2] = a2;
                gbuf[q][3] = a3;
            }
            __syncthreads();                                   // B: sums ready

            if (tid < 16) {
                // validate G (in-kernel GEMM producer); huge slack after t>~40
                const float* gptr = G1 + (size_t)t * NGATE + u0 + tid;
                for (int it = 0; it < SPIN_MAX; ++it) {
                    if (__ballot(isp(Gv0) | isp(Gv1) | isp(Gv2) | isp(Gv3)) == 0ULL)
                        break;
                    __builtin_amdgcn_s_sleep(1);
                    if (isp(Gv0)) Gv0 = agent_loadf(gptr);
                    if (isp(Gv1)) Gv1 = agent_loadf(gptr + 1024);
                    if (isp(Gv2)) Gv2 = agent_loadf(gptr + 2048);
                    if (isp(Gv3)) Gv3 = agent_loadf(gptr + 3072);
                }
                float gi = gbuf[tid][0] + Gv0;
                float gf = gbuf[tid][1] + Gv1;
                float gg = gbuf[tid][2] + Gv2;
                float go = gbuf[tid][3] + Gv3;
                float i_ = sigm(gi), f_ = sigm(gf), g_ = fast_tanh(gg), o_ = sigm(go);
                c1 = f_ * c1 + i_ * g_;
                float hn = o_ * fast_tanh(c1);
                float hnn = __shfl_down(hn, 1, 64);
                if (!(tid & 1))
                    agent_storeu(H1p + (size_t)t * 512 + (u0 >> 1) + (tid >> 1),
                                 pack_h(hn, hnn));
            }
            // cross-iteration prefetch: issue load of the row just produced
            if (tid < 512 && t < TSTEPS - 1) {
                pv = agent_loadu(H1p + (size_t)t * 512 + tid);
                PINU(pv);
            }
        }
    } else {
        // ---- GEMM phase: 4 teams x 256 threads, exactly 2 tiles each ----
        // work w in [0,1024): bm = w>>6 (t-block), bn = w&63 -> t-major
        // completion (G rows 0..511 after round 0). Fixed counts keep the
        // WG-wide __syncthreads aligned across teams.
        {
            const int team = tid >> 8;
            const int ttid = tid & 255;
            const int tg   = (wg - NWG_L1) * 4 + team;   // 0..511
#pragma unroll
            for (int r = 0; r < 2; ++r) {
                const int wk = tg + r * 512;
                gemm_tile(wk >> 6, wk & 63, ttid, Wih1, bih1, bhh1, G1,
                          xin, timev, AsT[team], BsT[team]);
            }
        }
        __syncthreads();

        // ---- Layers 2 & 3 (shared weights): WG owns 8 units ----
        const int ul = q >> 1;     // unit-local 0..7
        const int gp = q & 1;      // 0 -> gates (i,f), 1 -> gates (g,o)
        const int u0 = (wg - NWG_L1) << 3;
        const int u  = u0 + ul;
        unsigned wi[2][8], wh[2][8];
#pragma unroll
        for (int j = 0; j < 2; ++j) {
            const unsigned* ri = Wpi2 + (size_t)(((2 * gp + j) << 10) + u) * 512 + s;
            const unsigned* rh = Wph2 + (size_t)(((2 * gp + j) << 10) + u) * 512 + s;
#pragma unroll
            for (int m = 0; m < 8; ++m) {
                wi[j][m] = ri[64 * m];
                wh[j][m] = rh[64 * m];
            }
        }
        float bias0 = 0.f, bias1v = 0.f, bias2v = 0.f, bias3 = 0.f, cst = 0.f;
        if (tid < 16) {
            int uu = u0 + (tid & 7);
            bias0  = bih2[uu]        + bhh2[uu];
            bias1v = bih2[1024 + uu] + bhh2[1024 + uu];
            bias2v = bih2[2048 + uu] + bhh2[2048 + uu];
            bias3  = bih2[3072 + uu] + bhh2[3072 + uu];
            cst = (tid < 8) ? c0_2[u0 + tid] : c0_3[u0 + tid - 8];
        }
        unsigned pv1 = 0u;  // cross-iteration prefetch of h1 row
        if (tid < 512) pv1 = agent_loadu(H1p + tid);   // prologue: row 0

        // iteration t: layer2 tick t (needs h1[t], h2[t-1]) and
        //              layer3 tick t-1 (needs h2[t-1], h3[t-2])
        for (int t = 0; t <= TSTEPS; ++t) {
#pragma unroll
            for (int j = 0; j < 2; ++j)
#pragma unroll
                for (int m = 0; m < 8; ++m) { PINU(wi[j][m]); PINU(wh[j][m]); }

            const bool do2 = (t < TSTEPS);
            const bool do3 = (t >= 1);

            // ---- phase 0: stage h1[t] (slack row, prefetched) ----
            if (tid < 512 && do2) {
                const unsigned* p = H1p + (size_t)t * 512 + tid;
                unsigned v = pv1;
                for (int it = 0; it < SPIN_MAX; ++it) {
                    if (__ballot(v == POISON_U) == 0ULL) break;
                    __builtin_amdgcn_s_sleep(1);
                    if (v == POISON_U) v = agent_loadu(p);
                }
                shp1[tid] = v;
            }
            __syncthreads();                                   // A1: h1 staged

            // ---- phase 1: wi*h1 partial dots (overlaps peers' h2/h3 stores)
            float p20 = 0.f, p21 = 0.f;
#pragma unroll
            for (int m = 0; m < 8; ++m) {
                unsigned h1u = shp1[s + 64 * m];
                p20 = dot2f(h1u, wi[0][m], p20);
                p21 = dot2f(h1u, wi[1][m], p21);
            }

            // ---- phase 2: NOW poll the zero-slack rows h2[t-1], h3[t-2] ----
            if (tid < 512) {
                if (t == 0) {
                    shp2[tid] = pack_h(h0_2[2 * tid], h0_2[2 * tid + 1]);
                } else {
                    const unsigned* p = H2p + (size_t)(t - 1) * 512 + tid;
                    unsigned v = agent_loadu(p);
                    for (int it = 0; it < SPIN_MAX; ++it) {
                        if (__ballot(v == POISON_U) == 0ULL) break;
                        __builtin_amdgcn_s_sleep(1);
                        if (v == POISON_U) v = agent_loadu(p);
                    }
                    shp2[tid] = v;
                }
            } else {
                const int sid = tid - 512;
                if (t == 1) {
                    shp3[sid] = pack_h(h0_3[2 * sid], h0_3[2 * sid + 1]);
                } else if (t > 1) {
                    const unsigned* p = H3p + (size_t)(t - 2) * 512 + sid;
                    unsigned v = agent_loadu(p);
                    for (int it = 0; it < SPIN_MAX; ++it) {
                        if (__ballot(v == POISON_U) == 0ULL) break;
                        __builtin_amdgcn_s_sleep(1);
                        if (v == POISON_U) v = agent_loadu(p);
                    }
                    shp3[sid] = v;
                }
            }
            __syncthreads();                                   // A2: h2/h3 staged

            // ---- phase 3: remaining dots ----
            float p30 = 0.f, p31 = 0.f;
#pragma unroll
            for (int m = 0; m < 8; ++m) {
                unsigned h2u = shp2[s + 64 * m];
                unsigned h3u = shp3[s + 64 * m];
                p20 = dot2f(h2u, wh[0][m], p20);
                p21 = dot2f(h2u, wh[1][m], p21);
                p30 = dot2f(h2u, wi[0][m], p30);
                p31 = dot2f(h2u, wi[1][m], p31);
                p30 = dot2f(h3u, wh[0][m], p30);
                p31 = dot2f(h3u, wh[1][m], p31);
            }
            float s20 = wave_sum64_dpp(p20);
            float s21 = wave_sum64_dpp(p21);
            float s30 = wave_sum64_dpp(p30);
            float s31 = wave_sum64_dpp(p31);
            if (s == 63) {
                gbuf[ul][2 * gp]          = s20;
                gbuf[ul][2 * gp + 1]      = s21;
                gbuf[8 + ul][2 * gp]      = s30;
                gbuf[8 + ul][2 * gp + 1]  = s31;
            }
            __syncthreads();                                   // B: sums ready

            if (tid < 16) {
                const bool act = (tid < 8) ? do2 : do3;
                float hn = 0.f;
                if (act) {
                    float gi = gbuf[tid][0] + bias0;
                    float gf = gbuf[tid][1] + bias1v;
                    float gg = gbuf[tid][2] + bias2v;
                    float go = gbuf[tid][3] + bias3;
                    float i_ = sigm(gi), f_ = sigm(gf), g_ = fast_tanh(gg), o_ = sigm(go);
                    cst = f_ * cst + i_ * g_;
                    hn = o_ * fast_tanh(cst);
                }
                float hnn = __shfl_down(hn, 1, 64);
                if (act) {
                    if (tid < 8) {         // h2 units: packed store (4 uints/WG)
                        if (!(tid & 1))
                            agent_storeu(H2p + (size_t)t * 512 + (u0 >> 1) + (tid >> 1),
                                         pack_h(hn, hnn));
                    } else {               // h3 units: packed + fp32 for attn
                        if (!(tid & 1))
                            agent_storeu(H3p + (size_t)(t - 1) * 512 + (u0 >> 1) + ((tid - 8) >> 1),
                                         pack_h(hn, hnn));
                        H3f[(size_t)(t - 1) * HDIM + u0 + (tid - 8)] = hn;
                    }
                }
            }
            // cross-iteration prefetch of h1[t+1]
            if (tid < 512 && t < TSTEPS - 1) {
                pv1 = agent_loadu(H1p + (size_t)(t + 1) * 512 + tid);
                PINU(pv1);
            }
        }
    }
}

// ---------------------------------------------------------------------------
// Attention (unchanged, proven; reads fp32 H3f)
// ---------------------------------------------------------------------------
__global__ __launch_bounds__(256) void attn_dot(
    const float* __restrict__ H3, float* __restrict__ attn)
{
    const int t = blockIdx.x * 4 + (threadIdx.x >> 6);
    const int lane = threadIdx.x & 63;
    const float* hrow = H3 + (size_t)t * HDIM;
    const float* hf = H3 + (size_t)(TSTEPS - 1) * HDIM;
    float p = 0.f;
    for (int j = lane; j < HDIM; j += 64) p = fmaf(hrow[j], hf[j], p);
#pragma unroll
    for (int d = 32; d; d >>= 1) p += __shfl_down(p, d, 64);
    if (lane == 0) attn[t] = p;
}

__global__ __launch_bounds__(64) void softmax_1024(float* attn)
{
    const int lane = threadIdx.x;
    float vals[16];
    float m = -1e30f;
#pragma unroll
    for (int i = 0; i < 16; i++) {
        vals[i] = attn[lane + i * 64];
        m = fmaxf(m, vals[i]);
    }
#pragma unroll
    for (int d = 32; d; d >>= 1) m = fmaxf(m, __shfl_xor(m, d, 64));
    float s = 0.f;
#pragma unroll
    for (int i = 0; i < 16; i++) {
        vals[i] = expf(vals[i] - m);
        s += vals[i];
    }
#pragma unroll
    for (int d = 32; d; d >>= 1) s += __shfl_xor(s, d, 64);
    float inv = 1.f / s;
#pragma unroll
    for (int i = 0; i < 16; i++) attn[lane + i * 64] = vals[i] * inv;
}

__global__ __launch_bounds__(256) void context_kernel(
    const float* __restrict__ H3, const float* __restrict__ w,
    float* __restrict__ out)
{
    const int u = blockIdx.x * 4 + (threadIdx.x >> 6);
    const int lane = threadIdx.x & 63;
    float p = 0.f;
    for (int t = lane; t < TSTEPS; t += 64)
        p = fmaf(H3[(size_t)t * HDIM + u], w[t], p);
#pragma unroll
    for (int d = 32; d; d >>= 1) p += __shfl_down(p, d, 64);
    if (lane == 0) out[u] = p;
}

// ---------------------------------------------------------------------------
// Launch
// ---------------------------------------------------------------------------
extern "C" void kernel_launch(void* const* d_in, const int* in_sizes, int n_in,
                              void* d_out, int out_size, void* d_ws, size_t ws_size,
                              hipStream_t stream)
{
    const float* x     = (const float*)d_in[0];
    const float* timev = (const float*)d_in[1];
    const float* h0_1  = (const float*)d_in[2];
    const float* c0_1  = (const float*)d_in[3];
    const float* h0_2  = (const float*)d_in[4];
    const float* c0_2  = (const float*)d_in[5];
    const float* h0_3  = (const float*)d_in[6];
    const float* c0_3  = (const float*)d_in[7];
    const float* Wih1  = (const float*)d_in[8];
    const float* Whh1  = (const float*)d_in[9];
    const float* bih1  = (const float*)d_in[10];
    const float* bhh1  = (const float*)d_in[11];
    const float* Wih2  = (const float*)d_in[12];
    const float* Whh2  = (const float*)d_in[13];
    const float* bih2  = (const float*)d_in[14];
    const float* bhh2  = (const float*)d_in[15];

    // workspace carve (~50 MB)
    float* G      = (float*)d_ws;                             // 1024*4096 fp32
    unsigned* H1p = (unsigned*)(G + (size_t)TSTEPS * NGATE);  // 1024*512 uints
    unsigned* H2p = H1p + (size_t)TSTEPS * 512;
    unsigned* H3p = H2p + (size_t)TSTEPS * 512;
    float* H3f    = (float*)(H3p + (size_t)TSTEPS * 512);     // 1024*1024 fp32
    float* attn   = H3f + (size_t)TSTEPS * HDIM;              // 1024 fp32
    unsigned* Wp1  = (unsigned*)(attn + 1024);                // 4096*512 uints each
    unsigned* Wpi2 = Wp1 + (size_t)NGATE * 512;
    unsigned* Wph2 = Wpi2 + (size_t)NGATE * 512;
    float* out  = (float*)d_out;

    // Poison G + packed H rows (contiguous): the poll protocol depends on it.
    hipMemsetAsync(G, 0x7C,
                   (size_t)TSTEPS * NGATE * sizeof(float) +
                   (size_t)3 * TSTEPS * 512 * sizeof(unsigned), stream);

    // Pack the three scan weight matrices to f16 pairs (one-time).
    {
        const int n = NGATE * 512;
        pack_f16<<<dim3(n / 256), dim3(256), 0, stream>>>(Whh1, Wp1, n);
        pack_f16<<<dim3(n / 256), dim3(256), 0, stream>>>(Wih2, Wpi2, n);
        pack_f16<<<dim3(n / 256), dim3(256), 0, stream>>>(Whh2, Wph2, n);
    }

    // Fused scan + in-kernel G-GEMM (cooperative: 192 WGs x 1024 threads)
    {
        const unsigned* a0 = Wp1;  float* a1 = G;
        const unsigned* a2 = Wpi2; const unsigned* a3 = Wph2;
        const float* a4 = Wih1;  const float* a5 = bih1;  const float* a6 = bhh1;
        const float* a7 = x;     const float* a8 = timev;
        const float* a9 = bih2;  const float* a10 = bhh2;
        const float* a11 = h0_1; const float* a12 = c0_1;
        const float* a13 = h0_2; const float* a14 = c0_2;
        const float* a15 = h0_3; const float* a16 = c0_3;
        unsigned* a17 = H1p; unsigned* a18 = H2p; unsigned* a19 = H3p;
        float* a20 = H3f;
        void* args[] = {&a0,&a1,&a2,&a3,&a4,&a5,&a6,&a7,&a8,&a9,&a10,&a11,
                        &a12,&a13,&a14,&a15,&a16,&a17,&a18,&a19,&a20};
        hipLaunchCooperativeKernel((void*)fused_scan, dim3(NWG_TOT), dim3(1024),
                                   args, 0, stream);
    }

    // Attention
    attn_dot<<<dim3(256), dim3(256), 0, stream>>>(H3f, attn);
    softmax_1024<<<dim3(1), dim3(64), 0, stream>>>(attn);
    context_kernel<<<dim3(256), dim3(256), 0, stream>>>(H3f, attn, out);
}